// Round 1
// baseline (468.811 us; speedup 1.0000x reference)
//
#include <hip/hip_runtime.h>
#include <math.h>

#define T_LEN 1024
#define BATCH 1024
#define H 64
#define NB 4   // batches per block

typedef __attribute__((ext_vector_type(4))) int   i32x4;

#define L2E     1.44269504088896340736f
#define TWO_L2E 2.88539008177792681472f

__device__ __forceinline__ float fast_rcp(float x)   { return __builtin_amdgcn_rcpf(x); }
__device__ __forceinline__ float exp2f_fast(float x) { return __builtin_amdgcn_exp2f(x); }

// ===================== encoder =====================
// R12/R15 structure (grid 256 x 256thr, 1 block/CU, NB=4, lane owns one
// (batch,unit) cell) with two changes this round:
//
// R17a: digit-in-M-row MFMA packing. The old A tile was 4 batches x 4
// replicas (75% of M wasted, lanes read reg 0 only) and needed 3 MFMAs/gate
// for the two-digit product. New A tile packs rows 4q+0 = Aa(batch q),
// 4q+1 = Ab(batch q) (rows 4q+2,3 = harmless duplicates). Then per gate:
//   M1 = mfma(A, Ba): reg0 = Aa.Ba, reg1 = Ab.Ba
//   M2 = mfma(A, Bb): reg0 = Aa.Bb, reg1 = Ab.Bb  (<- previously dropped!)
//   S  = (M1[0]<<7) + M1[1] + M2[0] + (M2[1]>>7)   // now exact to 2^-21
// 2 independent MFMAs/gate (8/step, was 12) and ONE ds_read_b128 for A
// (was 2): each lane loads digit (l15&1) of batch (l15>>2).
//
// R17b: exp2-domain epilogue. Gate constants pre-scaled by {-L2E,-L2E,
// +2*L2E,-L2E} so S feeds v_exp_f32 via one fma (no per-exp mul); c kept
// in 2*log2e domain (cs), h kept in x8192 domain (h8k) so the 2c mul and
// the quantize mul leave the serial chain. Merged reciprocals kept (R16).
__global__ __launch_bounds__(256, 1) void encoder_kernel(
    const float* __restrict__ x,      // [T, BATCH]
    const float* __restrict__ Wih_e,  // [256, 1]
    const float* __restrict__ Whh_e,  // [256, 64]
    const float* __restrict__ bih_e,  // [256]
    const float* __restrict__ bhh_e,  // [256]
    float* __restrict__ h_enc)        // [BATCH, 64]
{
  // [parity][digit][bat*H + u]
  __shared__ __align__(16) signed char dig[2][2][NB * H];   // 1 KB
  __shared__ float x_lds[T_LEN * NB];                       // 16 KB

  const int tid  = threadIdx.x;
  const int lane = tid & 63;
  const int wv   = tid >> 6;        // unit-group (0..3)
  const int q    = lane >> 4;       // k-chunk for A/B fragments; cell batch
  const int l15  = lane & 15;
  const int b0   = blockIdx.x * NB;
  const int u    = wv * 16 + l15;   // this lane's hidden unit
  const int bat  = q;               // this lane's cell batch

  // ---- persistent weight digit fragments: 4 gates x {wa,wb}, 32 VGPRs ----
  i32x4 Ba[4], Bb[4];
  float wih_s[4], bias_s[4], kS[4];
  const float mg[4] = {-L2E, -L2E, TWO_L2E, -L2E};  // exp2-domain gate scales
  for (int g = 0; g < 4; ++g) {
    const int n = g * 64 + u;       // gate row
    const float* wp = &Whh_e[n * H + q * 16];
    union { i32x4 v; signed char c[16]; } ua, ub;
#pragma unroll
    for (int j = 0; j < 16; ++j) {
      const int wint = (int)rintf(wp[j] * 32768.f);   // |.| <= 4096
      const int wa = (wint + 64) >> 7;                // [-32, 32]
      const int wb = wint - (wa << 7);                // [-64, 63]
      ua.c[j] = (signed char)wa;
      ub.c[j] = (signed char)wb;
    }
    Ba[g] = ua.v; Bb[g] = ub.v;
    wih_s[g]  = Wih_e[n] * mg[g];
    bias_s[g] = (bih_e[n] + bhh_e[n]) * mg[g];
    kS[g]     = mg[g] * 0x1.0p-21f;
  }

  // A-fragment source: lane holds A row l15 = {batch l15>>2, digit l15&1},
  // k-bytes q*16..q*16+15. Rows with l15&2 are duplicates (never extracted).
  const signed char* ard[2];
  ard[0] = &dig[0][l15 & 1][(l15 >> 2) * H + q * 16];
  ard[1] = &dig[1][l15 & 1][(l15 >> 2) * H + q * 16];

  // ---- one-time staging: x (float4 rows, layout [t][b]) + zero digits ----
  for (int t = tid; t < T_LEN; t += 256)
    *(float4*)&x_lds[t * NB] = *(const float4*)&x[t * BATCH + b0];
  for (int i = tid; i < 2 * NB * H; i += 256)
    ((signed char*)dig[0])[i] = 0;      // h=0 -> both digits 0
  __syncthreads();

  float cs = 0.0f;        // cs = 2*log2e * c
  float h8k_last = 0.0f;  // h8k = 8192 * h
  const i32x4 izero = {0, 0, 0, 0};

#define ENC_STEP(P, TT)                                                        \
  {                                                                            \
    const i32x4 Am = *(const i32x4*)ard[P];                                    \
    const float xv = x_lds[(TT) * NB + bat];                                   \
    float arg[4];                                                              \
    _Pragma("unroll")                                                          \
    for (int g = 0; g < 4; ++g) {                                              \
      i32x4 M1 = __builtin_amdgcn_mfma_i32_16x16x64_i8(Am, Ba[g], izero, 0, 0, 0); \
      i32x4 M2 = __builtin_amdgcn_mfma_i32_16x16x64_i8(Am, Bb[g], izero, 0, 0, 0); \
      const int S = (M1[0] << 7) + (M1[1] + M2[0]) + (M2[1] >> 7);             \
      arg[g] = fmaf((float)S, kS[g], fmaf(xv, wih_s[g], bias_s[g]));           \
    }                                                                          \
    /* merged-reciprocal cell update, all-exp2 domain */                       \
    const float p  = exp2f_fast(arg[0]);      /* e^-G0  (i gate) */            \
    const float pf = exp2f_fast(arg[1]);      /* e^-G1  (f gate) */            \
    const float r  = exp2f_fast(arg[2]);      /* e^{2 G2} (g gate) */          \
    const float uo = exp2f_fast(arg[3]);      /* e^-G3  (o gate) */            \
    const float fv  = fast_rcp(1.0f + pf);                                     \
    const float igs = ((r - 1.0f) * TWO_L2E) * fast_rcp((1.0f + p) * (r + 1.0f)); \
    cs = fmaf(fv, cs, igs);                                                    \
    const float s = exp2f_fast(cs);           /* e^{2c} */                     \
    const float h8k = ((s - 1.0f) * 8192.0f) * fast_rcp((1.0f + uo) * (s + 1.0f)); \
    const int v  = (int)rintf(h8k);              /* [-8192, 8192] */           \
    const int ad = (v + 64) >> 7;                /* [-64, 64] */               \
    const int bd = v - (ad << 7);                /* [-64, 63] */               \
    dig[1 - (P)][0][bat * H + u] = (signed char)ad;                            \
    dig[1 - (P)][1][bat * H + u] = (signed char)bd;                            \
    h8k_last = h8k;                                                            \
    __syncthreads();                                                           \
  }

  for (int t = 0; t < T_LEN; t += 2) {
    ENC_STEP(0, t)
    ENC_STEP(1, t + 1)
  }
#undef ENC_STEP

  h_enc[(b0 + bat) * H + u] = h8k_last * 0x1.0p-13f;
}

// ===================== decoder =====================
// Wide form (validated): one lane per batch, 16 waves, grid 16, latency
// floor = two dependent trans rounds per step. This round: exp2-domain
// constants (no per-exp mul on the chain), c kept in 2*log2e domain, and
// next-step gate args computed directly from t = rcp(1+s) (h = ov*(1-2t)
// folded into the fma constants) -> one fewer fma on the h->h chain.
// 8-deep register store buffer keeps store retirement off the chain.
__global__ __launch_bounds__(64) void decoder_kernel(
    const float* __restrict__ h_enc,  // [BATCH, 64]
    const float* __restrict__ Wih,    // [4, 64]
    const float* __restrict__ Whh,    // [4, 1]
    const float* __restrict__ bih,    // [4]
    const float* __restrict__ bhh,    // [4]
    float* __restrict__ out)          // [T, BATCH]
{
  const int b = blockIdx.x * blockDim.x + threadIdx.x;

  float a0 = bih[0] + bhh[0];
  float a1 = bih[1] + bhh[1];
  float a2 = bih[2] + bhh[2];
  float a3 = bih[3] + bhh[3];
#pragma unroll 8
  for (int k = 0; k < H; ++k) {
    const float hv = h_enc[b * H + k];
    a0 = fmaf(Wih[0 * H + k], hv, a0);
    a1 = fmaf(Wih[1 * H + k], hv, a1);
    a2 = fmaf(Wih[2 * H + k], hv, a2);
    a3 = fmaf(Wih[3 * H + k], hv, a3);
  }
  // exp2-domain constants: sigmoid gates use -L2E, tanh gate +2*L2E
  const float wS0 = -L2E * Whh[0],     aS0 = -L2E * a0;      // i
  const float wS1 = -L2E * Whh[1],     aS1 = -L2E * a1;      // f
  const float wS2 = TWO_L2E * Whh[2],  aS2 = TWO_L2E * a2;   // g
  const float wS3 = -L2E * Whh[3],     aS3 = -L2E * a3;      // o

  float cs = 0.0f;                 // 2*log2e * c
  float ovp = 0.0f, tp = 0.0f;     // h = ovp*(1 - 2*tp); h0 = 0
  float* outp = out + b;
  for (int t = 0; t < T_LEN; t += 8) {
    float buf[8];
#pragma unroll
    for (int uu = 0; uu < 8; ++uu) {
      // gate args = wS*h + aS with h = ovp - 2*ovp*tp folded:
      // chain from tp is a single fma (ow* terms are off-chain).
      const float ow0 = ovp * wS0, ow1 = ovp * wS1;
      const float ow2 = ovp * wS2, ow3 = ovp * wS3;
      const float arg0 = fmaf(-2.0f * ow0, tp, ow0 + aS0);
      const float arg1 = fmaf(-2.0f * ow1, tp, ow1 + aS1);
      const float arg2 = fmaf(-2.0f * ow2, tp, ow2 + aS2);
      const float arg3 = fmaf(-2.0f * ow3, tp, ow3 + aS3);
      const float pi = exp2f_fast(arg0);
      const float pf = exp2f_fast(arg1);
      const float rg = exp2f_fast(arg2);
      const float po = exp2f_fast(arg3);
      const float iv = fast_rcp(1.0f + pi);
      const float fv = fast_rcp(1.0f + pf);
      const float gS = ((rg - 1.0f) * TWO_L2E) * fast_rcp(rg + 1.0f); // 2L2E*tanh(G2)
      cs = fmaf(fv, cs, iv * gS);
      const float s = exp2f_fast(cs);          // e^{2c}
      ovp = fast_rcp(1.0f + po);               // sigmoid(o)
      tp  = fast_rcp(1.0f + s);                // (1 - tanh(c))/2 factor
      buf[uu] = fmaf(-2.0f * ovp, tp, ovp);    // h = ov * tanh(c)
    }
#pragma unroll
    for (int uu = 0; uu < 8; ++uu)
      outp[(t + uu) * BATCH] = buf[uu];
  }
}

extern "C" void kernel_launch(void* const* d_in, const int* in_sizes, int n_in,
                              void* d_out, int out_size, void* d_ws, size_t ws_size,
                              hipStream_t stream) {
  const float* x     = (const float*)d_in[0];
  const float* Wih_e = (const float*)d_in[1];
  const float* Whh_e = (const float*)d_in[2];
  const float* bih_e = (const float*)d_in[3];
  const float* bhh_e = (const float*)d_in[4];
  const float* Wih_d = (const float*)d_in[5];
  const float* Whh_d = (const float*)d_in[6];
  const float* bih_d = (const float*)d_in[7];
  const float* bhh_d = (const float*)d_in[8];
  float* out = (float*)d_out;

  float* h_enc = (float*)d_ws;  // 1024*64*4 = 256 KB scratch

  encoder_kernel<<<BATCH / NB, 256, 0, stream>>>(x, Wih_e, Whh_e, bih_e, bhh_e, h_enc);
  decoder_kernel<<<BATCH / 64, 64, 0, stream>>>(h_enc, Wih_d, Whh_d, bih_d, bhh_d, out);
}

// Round 2
// 445.256 us; speedup vs baseline: 1.0529x; 1.0529x over previous
//
#include <hip/hip_runtime.h>
#include <math.h>

#define T_LEN 1024
#define BATCH 1024
#define H 64
#define NB 4   // batches per block

typedef __attribute__((ext_vector_type(4))) int   i32x4;

#define L2E     1.44269504088896340736f
#define TWO_L2E 2.88539008177792681472f

__device__ __forceinline__ float fast_rcp(float x)   { return __builtin_amdgcn_rcpf(x); }
__device__ __forceinline__ float exp2f_fast(float x) { return __builtin_amdgcn_exp2f(x); }
__device__ __forceinline__ float fast_sigmoid(float x) {
  return fast_rcp(1.0f + __expf(-x));
}
// sigmoid with pre-negated argument: sigmoid(x) where nx = -x is given
__device__ __forceinline__ float fast_sigmoid_n(float nx) {
  return fast_rcp(1.0f + __expf(nx));
}
// tanh(x) = 1 - 2/(1+exp(2x)) — exact identity; saturates correctly.
__device__ __forceinline__ float fast_tanh(float x) {
  return fmaf(-2.0f, fast_rcp(1.0f + __expf(2.0f * x)), 1.0f);
}

// ===================== encoder =====================
// Structure (validated R12..R17): grid 256 x 256thr, 1 block/CU, NB=4,
// lane owns one (batch,unit) cell. Occupancy is structurally pinned at
// 1 wave/SIMD (65536 cells = 1 lane/cell fills the machine), so the step
// time IS the serial chain: barrier -> ds_read A -> MFMA -> trans chain ->
// quantize -> ds_write -> barrier. R18 attacks the LDS-port and off-chain
// work, not MFMA count (R17 proved MFMA issue is hidden by latency).
//
// R17a (kept): digit-in-M-row MFMA packing. A rows 4q+0 = Aa(batch q),
// 4q+1 = Ab(batch q). Per gate:
//   M1 = mfma(A, Ba): reg0 = Aa.Ba, reg1 = Ab.Ba
//   M2 = mfma(A, Bb): reg0 = Aa.Bb, reg1 = Ab.Bb
//   S  = (M1[0]<<7) + (M1[1]+M2[0]) + (M2[1]>>7)   // exact to 2^-21
// 2 MFMAs/gate, ONE ds_read_b128 for A.
//
// R17b (kept): exp2-domain epilogue; c in 2*log2e domain, h in x8192
// domain; merged reciprocals (5 exp2 + 3 rcp per step).
//
// R18: x path off the per-step critical path. x_lds re-laid batch-major
// ([NB][T+4], 16B row pad so the 4 batch rows hit different banks), ONE
// float4 read per 4 steps, and all 16 gate-base fmas (xv*wih+bias)
// precomputed per 4-step group. Per-step LDS traffic drops from
// {b128 + b32 reads, 2 b8 writes} to {b128 read, 2 b8 writes}; the
// arg chain from MFMA is cvt + 1 fma.
__global__ __launch_bounds__(256, 1) void encoder_kernel(
    const float* __restrict__ x,      // [T, BATCH]
    const float* __restrict__ Wih_e,  // [256, 1]
    const float* __restrict__ Whh_e,  // [256, 64]
    const float* __restrict__ bih_e,  // [256]
    const float* __restrict__ bhh_e,  // [256]
    float* __restrict__ h_enc)        // [BATCH, 64]
{
  // [parity][digit][bat*H + u]
  __shared__ __align__(16) signed char dig[2][2][NB * H];   // 1 KB
  __shared__ __align__(16) float x_lds[NB][T_LEN + 4];      // 16.06 KB, row pad = 16B

  const int tid  = threadIdx.x;
  const int lane = tid & 63;
  const int wv   = tid >> 6;        // unit-group (0..3)
  const int q    = lane >> 4;       // k-chunk for A/B fragments; cell batch
  const int l15  = lane & 15;
  const int b0   = blockIdx.x * NB;
  const int u    = wv * 16 + l15;   // this lane's hidden unit
  const int bat  = q;               // this lane's cell batch

  // ---- persistent weight digit fragments: 4 gates x {wa,wb}, 32 VGPRs ----
  i32x4 Ba[4], Bb[4];
  float wih_s[4], bias_s[4], kS[4];
  const float mg[4] = {-L2E, -L2E, TWO_L2E, -L2E};  // exp2-domain gate scales
  for (int g = 0; g < 4; ++g) {
    const int n = g * 64 + u;       // gate row
    const float* wp = &Whh_e[n * H + q * 16];
    union { i32x4 v; signed char c[16]; } ua, ub;
#pragma unroll
    for (int j = 0; j < 16; ++j) {
      const int wint = (int)rintf(wp[j] * 32768.f);   // |.| <= 4096
      const int wa = (wint + 64) >> 7;                // [-32, 32]
      const int wb = wint - (wa << 7);                // [-64, 63]
      ua.c[j] = (signed char)wa;
      ub.c[j] = (signed char)wb;
    }
    Ba[g] = ua.v; Bb[g] = ub.v;
    wih_s[g]  = Wih_e[n] * mg[g];
    bias_s[g] = (bih_e[n] + bhh_e[n]) * mg[g];
    kS[g]     = mg[g] * 0x1.0p-21f;
  }

  // A-fragment source: lane holds A row l15 = {batch l15>>2, digit l15&1},
  // k-bytes q*16..q*16+15. Rows with l15&2 are duplicates (never extracted).
  const signed char* ard[2];
  ard[0] = &dig[0][l15 & 1][(l15 >> 2) * H + q * 16];
  ard[1] = &dig[1][l15 & 1][(l15 >> 2) * H + q * 16];

  // ---- one-time staging: x transposed to [bat][t] + zero digits ----
  for (int t = tid; t < T_LEN; t += 256) {
    const float4 xv = *(const float4*)&x[t * BATCH + b0];
    x_lds[0][t] = xv.x;
    x_lds[1][t] = xv.y;
    x_lds[2][t] = xv.z;
    x_lds[3][t] = xv.w;
  }
  for (int i = tid; i < 2 * NB * H; i += 256)
    ((signed char*)dig[0])[i] = 0;      // h=0 -> both digits 0
  __syncthreads();

  float cs = 0.0f;        // cs = 2*log2e * c
  float h8k_last = 0.0f;  // h8k = 8192 * h
  const i32x4 izero = {0, 0, 0, 0};

#define ENC_STEP(P, BASE)                                                      \
  {                                                                            \
    const i32x4 Am = *(const i32x4*)ard[P];                                    \
    float arg[4];                                                              \
    _Pragma("unroll")                                                          \
    for (int g = 0; g < 4; ++g) {                                              \
      i32x4 M1 = __builtin_amdgcn_mfma_i32_16x16x64_i8(Am, Ba[g], izero, 0, 0, 0); \
      i32x4 M2 = __builtin_amdgcn_mfma_i32_16x16x64_i8(Am, Bb[g], izero, 0, 0, 0); \
      const int S = (M1[0] << 7) + (M1[1] + M2[0]) + (M2[1] >> 7);             \
      arg[g] = fmaf((float)S, kS[g], (BASE)[g]);                               \
    }                                                                          \
    /* merged-reciprocal cell update, all-exp2 domain */                       \
    const float p  = exp2f_fast(arg[0]);      /* e^-G0  (i gate) */            \
    const float pf = exp2f_fast(arg[1]);      /* e^-G1  (f gate) */            \
    const float r  = exp2f_fast(arg[2]);      /* e^{2 G2} (g gate) */          \
    const float uo = exp2f_fast(arg[3]);      /* e^-G3  (o gate) */            \
    const float fv  = fast_rcp(1.0f + pf);                                     \
    const float igs = ((r - 1.0f) * TWO_L2E) * fast_rcp((1.0f + p) * (r + 1.0f)); \
    cs = fmaf(fv, cs, igs);                                                    \
    const float s = exp2f_fast(cs);           /* e^{2c} */                     \
    const float h8k = ((s - 1.0f) * 8192.0f) * fast_rcp((1.0f + uo) * (s + 1.0f)); \
    const int v  = (int)rintf(h8k);              /* [-8192, 8192] */           \
    const int ad = (v + 64) >> 7;                /* [-64, 64] */               \
    const int bd = v - (ad << 7);                /* [-64, 63] */               \
    dig[1 - (P)][0][bat * H + u] = (signed char)ad;                            \
    dig[1 - (P)][1][bat * H + u] = (signed char)bd;                            \
    h8k_last = h8k;                                                            \
    __syncthreads();                                                           \
  }

  for (int t = 0; t < T_LEN; t += 4) {
    // one b128 x-read + 16 fma per 4 steps, all off the serial chain
    const float4 xf = *(const float4*)&x_lds[bat][t];
    float base[4][4];
#pragma unroll
    for (int ts = 0; ts < 4; ++ts) {
      const float xv = ((const float*)&xf)[ts];
#pragma unroll
      for (int g = 0; g < 4; ++g)
        base[ts][g] = fmaf(xv, wih_s[g], bias_s[g]);
    }
    ENC_STEP(0, base[0])
    ENC_STEP(1, base[1])
    ENC_STEP(0, base[2])
    ENC_STEP(1, base[3])
  }
#undef ENC_STEP

  h_enc[(b0 + bat) * H + u] = h8k_last * 0x1.0p-13f;
}

// ===================== decoder =====================
// Wide form (validated at ~123us): one lane per batch, 16 waves, grid 16.
// At its latency floor (~290 cyc/step: two dependent exp->rcp pairs on the
// h->c->h critical path; only 1024 independent chains -> 16 waves). Fusion
// measured 2.5x worse (R9-R11); periodicity exit never triggers (R14).
// R17's arg-folding variant REGRESSED ~14us (extra off-chain VALU ops are
// not free at 1 wave/SIMD) — reverted verbatim to the measured form.
// 8-deep register store buffer keeps store retirement off the chain.
__global__ __launch_bounds__(64) void decoder_kernel(
    const float* __restrict__ h_enc,  // [BATCH, 64]
    const float* __restrict__ Wih,    // [4, 64]
    const float* __restrict__ Whh,    // [4, 1]
    const float* __restrict__ bih,    // [4]
    const float* __restrict__ bhh,    // [4]
    float* __restrict__ out)          // [T, BATCH]
{
  const int b = blockIdx.x * blockDim.x + threadIdx.x;

  float a0 = bih[0] + bhh[0];
  float a1 = bih[1] + bhh[1];
  float a2 = bih[2] + bhh[2];
  float a3 = bih[3] + bhh[3];
#pragma unroll 8
  for (int k = 0; k < H; ++k) {
    const float hv = h_enc[b * H + k];
    a0 = fmaf(Wih[0 * H + k], hv, a0);
    a1 = fmaf(Wih[1 * H + k], hv, a1);
    a2 = fmaf(Wih[2 * H + k], hv, a2);
    a3 = fmaf(Wih[3 * H + k], hv, a3);
  }
  const float w0 = Whh[0], w1 = Whh[1], w2 = Whh[2], w3 = Whh[3];
  const float na0 = -a0, nw0 = -w0;   // i gate, negated
  const float na1 = -a1, nw1 = -w1;   // f gate, negated
  const float na3 = -a3, nw3 = -w3;   // o gate, negated

  float h = 0.0f, c = 0.0f;
  float* outp = out + b;
  for (int t = 0; t < T_LEN; t += 8) {
    float buf[8];
#pragma unroll
    for (int uu = 0; uu < 8; ++uu) {
      const float iv = fast_sigmoid_n(fmaf(nw0, h, na0));
      const float fv = fast_sigmoid_n(fmaf(nw1, h, na1));
      const float gv = fast_tanh(fmaf(w2, h, a2));
      const float ov = fast_sigmoid_n(fmaf(nw3, h, na3));
      c = fmaf(fv, c, iv * gv);
      h = ov * fast_tanh(c);
      buf[uu] = h;
    }
#pragma unroll
    for (int uu = 0; uu < 8; ++uu)
      outp[(t + uu) * BATCH] = buf[uu];
  }
}

extern "C" void kernel_launch(void* const* d_in, const int* in_sizes, int n_in,
                              void* d_out, int out_size, void* d_ws, size_t ws_size,
                              hipStream_t stream) {
  const float* x     = (const float*)d_in[0];
  const float* Wih_e = (const float*)d_in[1];
  const float* Whh_e = (const float*)d_in[2];
  const float* bih_e = (const float*)d_in[3];
  const float* bhh_e = (const float*)d_in[4];
  const float* Wih_d = (const float*)d_in[5];
  const float* Whh_d = (const float*)d_in[6];
  const float* bih_d = (const float*)d_in[7];
  const float* bhh_d = (const float*)d_in[8];
  float* out = (float*)d_out;

  float* h_enc = (float*)d_ws;  // 1024*64*4 = 256 KB scratch

  encoder_kernel<<<BATCH / NB, 256, 0, stream>>>(x, Wih_e, Whh_e, bih_e, bhh_e, h_enc);
  decoder_kernel<<<BATCH / 64, 64, 0, stream>>>(h_enc, Wih_d, Whh_d, bih_d, bhh_d, out);
}

// Round 3
// 406.697 us; speedup vs baseline: 1.1527x; 1.0948x over previous
//
#include <hip/hip_runtime.h>
#include <math.h>

#define T_LEN 1024
#define BATCH 1024
#define H 64
#define NB 4   // batches per block

typedef __attribute__((ext_vector_type(4))) int   i32x4;

#define L2E     1.44269504088896340736f
#define TWO_L2E 2.88539008177792681472f

__device__ __forceinline__ float fast_rcp(float x)   { return __builtin_amdgcn_rcpf(x); }
__device__ __forceinline__ float exp2f_fast(float x) { return __builtin_amdgcn_exp2f(x); }

// ===================== encoder =====================
// Structure (validated R12..R18): grid 256 x 256thr, 1 block/CU, NB=4,
// lane owns one (batch,unit) cell. Occupancy structurally pinned at
// 1 wave/SIMD (65536 cells = 1 lane/cell fills the machine), so step time =
// serial chain: barrier -> ds_read A -> 8 MFMA (~160 cyc/SIMD issue, floor
// for the 2-digit scheme) -> epilogue VALU (biggest: ~49% busy) -> quantize
// -> ds_write -> barrier.
//
// R17a (kept): digit-in-M-row MFMA packing. A rows 4q+0 = Aa(batch q),
// 4q+1 = Ab(batch q). Per gate:
//   M1 = mfma(A, Ba): reg0 = Aa.Ba, reg1 = Ab.Ba
//   M2 = mfma(A, Bb): reg0 = Aa.Bb
//   S  = (M1[0]<<7) + M1[1] + M2[0]
// (R19: M2[1]>>7 term dropped again — R16 measured identical absmax
// without it; saves 8 int ops/step.)
// R17b (kept): exp2-domain epilogue; c in 2*log2e domain, h in x8192 domain.
// R18 (kept): x batch-major in LDS, one float4 read + 16 base-fmas per
// 4 steps, all off the serial chain.
// R19: fma-formed epilogue products: (1+p)(r+1) = fma(p,r1,r1),
// (r-1)*2L2E = fma(r,2L2E,-2L2E), same for the s-layer. ~14 fewer VALU
// issue slots/step on a pipe that is the dominant consumer at 1 wave/SIMD.
__global__ __launch_bounds__(256, 1) void encoder_kernel(
    const float* __restrict__ x,      // [T, BATCH]
    const float* __restrict__ Wih_e,  // [256, 1]
    const float* __restrict__ Whh_e,  // [256, 64]
    const float* __restrict__ bih_e,  // [256]
    const float* __restrict__ bhh_e,  // [256]
    float* __restrict__ h_enc)        // [BATCH, 64]
{
  // [parity][digit][bat*H + u]
  __shared__ __align__(16) signed char dig[2][2][NB * H];   // 1 KB
  __shared__ __align__(16) float x_lds[NB][T_LEN + 4];      // 16.06 KB, row pad = 16B

  const int tid  = threadIdx.x;
  const int lane = tid & 63;
  const int wv   = tid >> 6;        // unit-group (0..3)
  const int q    = lane >> 4;       // k-chunk for A/B fragments; cell batch
  const int l15  = lane & 15;
  const int b0   = blockIdx.x * NB;
  const int u    = wv * 16 + l15;   // this lane's hidden unit
  const int bat  = q;               // this lane's cell batch

  // ---- persistent weight digit fragments: 4 gates x {wa,wb}, 32 VGPRs ----
  i32x4 Ba[4], Bb[4];
  float wih_s[4], bias_s[4], kS[4];
  const float mg[4] = {-L2E, -L2E, TWO_L2E, -L2E};  // exp2-domain gate scales
  for (int g = 0; g < 4; ++g) {
    const int n = g * 64 + u;       // gate row
    const float* wp = &Whh_e[n * H + q * 16];
    union { i32x4 v; signed char c[16]; } ua, ub;
#pragma unroll
    for (int j = 0; j < 16; ++j) {
      const int wint = (int)rintf(wp[j] * 32768.f);   // |.| <= 4096
      const int wa = (wint + 64) >> 7;                // [-32, 32]
      const int wb = wint - (wa << 7);                // [-64, 63]
      ua.c[j] = (signed char)wa;
      ub.c[j] = (signed char)wb;
    }
    Ba[g] = ua.v; Bb[g] = ub.v;
    wih_s[g]  = Wih_e[n] * mg[g];
    bias_s[g] = (bih_e[n] + bhh_e[n]) * mg[g];
    kS[g]     = mg[g] * 0x1.0p-21f;
  }

  // A-fragment source: lane holds A row l15 = {batch l15>>2, digit l15&1},
  // k-bytes q*16..q*16+15. Rows with l15&2 are duplicates (never extracted).
  const signed char* ard[2];
  ard[0] = &dig[0][l15 & 1][(l15 >> 2) * H + q * 16];
  ard[1] = &dig[1][l15 & 1][(l15 >> 2) * H + q * 16];

  // ---- one-time staging: x transposed to [bat][t] + zero digits ----
  for (int t = tid; t < T_LEN; t += 256) {
    const float4 xv = *(const float4*)&x[t * BATCH + b0];
    x_lds[0][t] = xv.x;
    x_lds[1][t] = xv.y;
    x_lds[2][t] = xv.z;
    x_lds[3][t] = xv.w;
  }
  for (int i = tid; i < 2 * NB * H; i += 256)
    ((signed char*)dig[0])[i] = 0;      // h=0 -> both digits 0
  __syncthreads();

  float cs = 0.0f;        // cs = 2*log2e * c
  float h8k_last = 0.0f;  // h8k = 8192 * h
  const i32x4 izero = {0, 0, 0, 0};

#define ENC_STEP(P, BASE)                                                      \
  {                                                                            \
    const i32x4 Am = *(const i32x4*)ard[P];                                    \
    float arg[4];                                                              \
    _Pragma("unroll")                                                          \
    for (int g = 0; g < 4; ++g) {                                              \
      i32x4 M1 = __builtin_amdgcn_mfma_i32_16x16x64_i8(Am, Ba[g], izero, 0, 0, 0); \
      i32x4 M2 = __builtin_amdgcn_mfma_i32_16x16x64_i8(Am, Bb[g], izero, 0, 0, 0); \
      const int S = (M1[0] << 7) + (M1[1] + M2[0]);                            \
      arg[g] = fmaf((float)S, kS[g], (BASE)[g]);                               \
    }                                                                          \
    /* merged-reciprocal cell update, all-exp2 domain, fma-formed */           \
    const float p  = exp2f_fast(arg[0]);      /* e^-G0  (i gate) */            \
    const float pf = exp2f_fast(arg[1]);      /* e^-G1  (f gate) */            \
    const float r  = exp2f_fast(arg[2]);      /* e^{2 G2} (g gate) */          \
    const float uo = exp2f_fast(arg[3]);      /* e^-G3  (o gate) */            \
    const float fv  = fast_rcp(1.0f + pf);                                     \
    const float r1  = r + 1.0f;                                                \
    const float den = fmaf(p, r1, r1);            /* (1+p)(1+r) */             \
    const float rm  = fmaf(r, TWO_L2E, -TWO_L2E); /* 2L2E*(r-1) */             \
    cs = fmaf(fv, cs, rm * fast_rcp(den));                                     \
    const float s  = exp2f_fast(cs);          /* e^{2c} */                     \
    const float s1 = s + 1.0f;                                                 \
    const float den2 = fmaf(uo, s1, s1);          /* (1+uo)(1+s) */            \
    const float sm   = fmaf(s, 8192.0f, -8192.0f);/* 8192*(s-1) */             \
    const float h8k = sm * fast_rcp(den2);                                     \
    const int v  = (int)rintf(h8k);              /* [-8192, 8192] */           \
    const int ad = (v + 64) >> 7;                /* [-64, 64] */               \
    const int bd = v - (ad << 7);                /* [-64, 63] */               \
    dig[1 - (P)][0][bat * H + u] = (signed char)ad;                            \
    dig[1 - (P)][1][bat * H + u] = (signed char)bd;                            \
    h8k_last = h8k;                                                            \
    __syncthreads();                                                           \
  }

  for (int t = 0; t < T_LEN; t += 4) {
    // one b128 x-read + 16 fma per 4 steps, all off the serial chain
    const float4 xf = *(const float4*)&x_lds[bat][t];
    float base[4][4];
#pragma unroll
    for (int ts = 0; ts < 4; ++ts) {
      const float xv = ((const float*)&xf)[ts];
#pragma unroll
      for (int g = 0; g < 4; ++g)
        base[ts][g] = fmaf(xv, wih_s[g], bias_s[g]);
    }
    ENC_STEP(0, base[0])
    ENC_STEP(1, base[1])
    ENC_STEP(0, base[2])
    ENC_STEP(1, base[3])
  }
#undef ENC_STEP

  h_enc[(b0 + bat) * H + u] = h8k_last * 0x1.0p-13f;
}

// ===================== decoder =====================
// Wide form (validated ~123-125us): one lane per batch, 16 waves, grid 16,
// latency floor = two dependent trans rounds per step on the h->c->h chain.
// R19: the SAFE half of R17's exp2 folding — gate constants pre-scaled by
// -L2E / +2L2E (removes the 4 __expf-internal muls), c kept in 2L2E domain
// (removes the tanh-input muls), but the h recurrence stays EXPLICIT
// (R17's regression was the ovp/tp refactor's extra ow-muls, not the fold).
// Strictly fewer issue ops and a shorter h->arg->exp2 chain than the
// measured form. 8-deep register store buffer keeps stores off the chain.
__global__ __launch_bounds__(64) void decoder_kernel(
    const float* __restrict__ h_enc,  // [BATCH, 64]
    const float* __restrict__ Wih,    // [4, 64]
    const float* __restrict__ Whh,    // [4, 1]
    const float* __restrict__ bih,    // [4]
    const float* __restrict__ bhh,    // [4]
    float* __restrict__ out)          // [T, BATCH]
{
  const int b = blockIdx.x * blockDim.x + threadIdx.x;

  float a0 = bih[0] + bhh[0];
  float a1 = bih[1] + bhh[1];
  float a2 = bih[2] + bhh[2];
  float a3 = bih[3] + bhh[3];
#pragma unroll 8
  for (int k = 0; k < H; ++k) {
    const float hv = h_enc[b * H + k];
    a0 = fmaf(Wih[0 * H + k], hv, a0);
    a1 = fmaf(Wih[1 * H + k], hv, a1);
    a2 = fmaf(Wih[2 * H + k], hv, a2);
    a3 = fmaf(Wih[3 * H + k], hv, a3);
  }
  // exp2-domain constants: sigmoid gates scaled by -L2E, tanh gate +2*L2E
  const float wS0 = -L2E * Whh[0],     aS0 = -L2E * a0;      // i
  const float wS1 = -L2E * Whh[1],     aS1 = -L2E * a1;      // f
  const float wS2 = TWO_L2E * Whh[2],  aS2 = TWO_L2E * a2;   // g
  const float wS3 = -L2E * Whh[3],     aS3 = -L2E * a3;      // o

  float h = 0.0f, cs = 0.0f;   // cs = 2*log2e * c
  float* outp = out + b;
  for (int t = 0; t < T_LEN; t += 8) {
    float buf[8];
#pragma unroll
    for (int uu = 0; uu < 8; ++uu) {
      const float pi = exp2f_fast(fmaf(wS0, h, aS0));
      const float pf = exp2f_fast(fmaf(wS1, h, aS1));
      const float rg = exp2f_fast(fmaf(wS2, h, aS2));
      const float po = exp2f_fast(fmaf(wS3, h, aS3));
      const float iv = fast_rcp(1.0f + pi);
      const float fv = fast_rcp(1.0f + pf);
      const float ov = fast_rcp(1.0f + po);
      const float gm = fmaf(rg, TWO_L2E, -TWO_L2E);      // 2L2E*(rg-1)
      const float gt = gm * fast_rcp(rg + 1.0f);         // 2L2E*tanh(G2)
      cs = fmaf(fv, cs, iv * gt);
      const float s  = exp2f_fast(cs);                   // e^{2c}
      const float tc = fast_rcp(1.0f + s);
      h = fmaf(-2.0f * ov, tc, ov);                      // ov * tanh(c)
      buf[uu] = h;
    }
#pragma unroll
    for (int uu = 0; uu < 8; ++uu)
      outp[(t + uu) * BATCH] = buf[uu];
  }
}

extern "C" void kernel_launch(void* const* d_in, const int* in_sizes, int n_in,
                              void* d_out, int out_size, void* d_ws, size_t ws_size,
                              hipStream_t stream) {
  const float* x     = (const float*)d_in[0];
  const float* Wih_e = (const float*)d_in[1];
  const float* Whh_e = (const float*)d_in[2];
  const float* bih_e = (const float*)d_in[3];
  const float* bhh_e = (const float*)d_in[4];
  const float* Wih_d = (const float*)d_in[5];
  const float* Whh_d = (const float*)d_in[6];
  const float* bih_d = (const float*)d_in[7];
  const float* bhh_d = (const float*)d_in[8];
  float* out = (float*)d_out;

  float* h_enc = (float*)d_ws;  // 1024*64*4 = 256 KB scratch

  encoder_kernel<<<BATCH / NB, 256, 0, stream>>>(x, Wih_e, Whh_e, bih_e, bhh_e, h_enc);
  decoder_kernel<<<BATCH / 64, 64, 0, stream>>>(h_enc, Wih_d, Whh_d, bih_d, bhh_d, out);
}

// Round 4
// 357.301 us; speedup vs baseline: 1.3121x; 1.1382x over previous
//
#include <hip/hip_runtime.h>
#include <math.h>

#define T_LEN 1024
#define BATCH 1024
#define H 64
#define NB 4   // batches per block

typedef __attribute__((ext_vector_type(8))) _Float16 f16x8;
typedef __attribute__((ext_vector_type(4))) float    f32x4;

#define L2E     1.44269504088896340736f
#define TWO_L2E 2.88539008177792681472f

__device__ __forceinline__ float fast_rcp(float x)   { return __builtin_amdgcn_rcpf(x); }
__device__ __forceinline__ float exp2f_fast(float x) { return __builtin_amdgcn_exp2f(x); }

// ===================== encoder =====================
// Structure (validated R12..R19): grid 256 x 256thr, 1 block/CU, NB=4,
// lane owns one (batch,unit) cell; 1 wave/SIMD structurally. At single-wave
// issue (~5-6 cyc/instr) the step cost IS the instruction count on the
// serial stream (R19 post-mortem: VALUBusy 45% = ~307cyc for ~55 ops).
//
// R20: h exchanged as fp16, MFMA switched to mfma_f32_16x16x32_f16.
// Kills the entire fixed-point apparatus (~20 instrs/step): S-assembly
// (4x shl/add/add/cvt) and digit quantize (rint/add/shr/mad + 2 b8 writes)
// are replaced by {fma per gate} + {1 cvt_f16 + 1 b16 write}. Same MFMA
// count (8/step: 4 gates x 2 chained k=32 halves; f16 rate = i8 rate
// per-instr). Justified by R17-R19 evidence that absmax (2^-11, pinned)
// is decoder-dominated: encoder h-precision has slack (fp16 h err ~1.2e-4
// vs 6.1e-5 for the old x8192 grid).
//
// h-state LDS layout [parity][jchunk(8)][bat(4)][8 f16]: unit-chunk-major
// so each b128 A-read is exactly 2-way bank-aliased (free, m136) instead
// of the old 4-way. A-frag: lane (row l15) reads hbuf[P][khalf*4+q][l15>>2]
// = units khalf*32+q*8..+7 of batch l15>>2, matching the f16 MFMA A layout
// (row = l&15, k = (l>>4)*8 + j; mirrors the m89-verified bf16 layout).
//
// R17b/R19 epilogue kept: exp2-domain, merged reciprocals, fma-formed
// products; c in 2*log2e domain. R18 kept: x batch-major, one float4 +
// 16 base-fmas per 4 steps, off the serial chain.
__global__ __launch_bounds__(256, 1) void encoder_kernel(
    const float* __restrict__ x,      // [T, BATCH]
    const float* __restrict__ Wih_e,  // [256, 1]
    const float* __restrict__ Whh_e,  // [256, 64]
    const float* __restrict__ bih_e,  // [256]
    const float* __restrict__ bhh_e,  // [256]
    float* __restrict__ h_enc)        // [BATCH, 64]
{
  // [parity][jchunk][bat][8] : unit u lives at jchunk u>>3, slot u&7
  __shared__ __align__(16) _Float16 hbuf[2][8][NB][8];    // 1 KB
  __shared__ __align__(16) float x_lds[NB][T_LEN + 4];    // 16.06 KB

  const int tid  = threadIdx.x;
  const int lane = tid & 63;
  const int wv   = tid >> 6;        // unit-group (0..3)
  const int q    = lane >> 4;       // k-chunk for A/B fragments; cell batch
  const int l15  = lane & 15;
  const int b0   = blockIdx.x * NB;
  const int u    = wv * 16 + l15;   // this lane's hidden unit
  const int bat  = q;               // this lane's cell batch

  // ---- persistent f16 weight fragments: 4 gates x 2 k-halves, 32 VGPRs ----
  f16x8 Bh[4][2];
  float wih_s[4], bias_s[4], kS[4];
  const float mg[4] = {-L2E, -L2E, TWO_L2E, -L2E};  // exp2-domain gate scales
  for (int g = 0; g < 4; ++g) {
    const int n = g * 64 + u;       // gate row
#pragma unroll
    for (int hf = 0; hf < 2; ++hf) {
      f16x8 bv;
#pragma unroll
      for (int j = 0; j < 8; ++j)
        bv[j] = (_Float16)Whh_e[n * H + hf * 32 + q * 8 + j];
      Bh[g][hf] = bv;
    }
    wih_s[g]  = Wih_e[n] * mg[g];
    bias_s[g] = (bih_e[n] + bhh_e[n]) * mg[g];
    kS[g]     = mg[g];
  }

  // A-fragment read base (row = l15 -> batch l15>>2), k-chunk q; the
  // second k-half sits +128 f16 further ([jchunk] stride 32 f16, +4 chunks).
  const _Float16* ar0[2] = { &hbuf[0][q][l15 >> 2][0], &hbuf[1][q][l15 >> 2][0] };
  // write target for parity P writes into buffer 1-P
  _Float16* wrp[2] = { &hbuf[1][u >> 3][bat][u & 7], &hbuf[0][u >> 3][bat][u & 7] };

  // ---- one-time staging: x transposed to [bat][t] + zero h-state ----
  for (int t = tid; t < T_LEN; t += 256) {
    const float4 xv = *(const float4*)&x[t * BATCH + b0];
    x_lds[0][t] = xv.x;
    x_lds[1][t] = xv.y;
    x_lds[2][t] = xv.z;
    x_lds[3][t] = xv.w;
  }
  for (int i = tid; i < 2 * 8 * NB * 8; i += 256)
    ((_Float16*)hbuf)[i] = (_Float16)0.0f;   // h=0
  __syncthreads();

  float cs = 0.0f;       // cs = 2*log2e * c
  float h_last = 0.0f;
  const f32x4 fzero = {0.0f, 0.0f, 0.0f, 0.0f};

#define ENC_STEP(P, BASE)                                                      \
  {                                                                            \
    const f16x8 A1 = *(const f16x8*)(ar0[P]);                                  \
    const f16x8 A2 = *(const f16x8*)(ar0[P] + 128);                            \
    float arg[4];                                                              \
    _Pragma("unroll")                                                          \
    for (int g = 0; g < 4; ++g) {                                              \
      f32x4 D = __builtin_amdgcn_mfma_f32_16x16x32_f16(A1, Bh[g][0], fzero, 0, 0, 0); \
      D = __builtin_amdgcn_mfma_f32_16x16x32_f16(A2, Bh[g][1], D, 0, 0, 0);    \
      arg[g] = fmaf(D[0], kS[g], (BASE)[g]);                                   \
    }                                                                          \
    /* merged-reciprocal cell update, all-exp2 domain, fma-formed */           \
    const float p  = exp2f_fast(arg[0]);      /* e^-G0  (i gate) */            \
    const float pf = exp2f_fast(arg[1]);      /* e^-G1  (f gate) */            \
    const float r  = exp2f_fast(arg[2]);      /* e^{2 G2} (g gate) */          \
    const float uo = exp2f_fast(arg[3]);      /* e^-G3  (o gate) */            \
    const float fv  = fast_rcp(1.0f + pf);                                     \
    const float r1  = r + 1.0f;                                                \
    const float den = fmaf(p, r1, r1);            /* (1+p)(1+r) */             \
    const float rm  = fmaf(r, TWO_L2E, -TWO_L2E); /* 2L2E*(r-1) */             \
    cs = fmaf(fv, cs, rm * fast_rcp(den));                                     \
    const float s  = exp2f_fast(cs);          /* e^{2c} */                     \
    const float s1 = s + 1.0f;                                                 \
    const float den2 = fmaf(uo, s1, s1);          /* (1+uo)(1+s) */            \
    const float h  = (s - 1.0f) * fast_rcp(den2); /* o*tanh(c) */              \
    *wrp[P] = (_Float16)h;                                                     \
    h_last = h;                                                                \
    __syncthreads();                                                           \
  }

  for (int t = 0; t < T_LEN; t += 4) {
    // one b128 x-read + 16 fma per 4 steps, all off the serial chain
    const float4 xf = *(const float4*)&x_lds[bat][t];
    float base[4][4];
#pragma unroll
    for (int ts = 0; ts < 4; ++ts) {
      const float xv = ((const float*)&xf)[ts];
#pragma unroll
      for (int g = 0; g < 4; ++g)
        base[ts][g] = fmaf(xv, wih_s[g], bias_s[g]);
    }
    ENC_STEP(0, base[0])
    ENC_STEP(1, base[1])
    ENC_STEP(0, base[2])
    ENC_STEP(1, base[3])
  }
#undef ENC_STEP

  // output the full-f32 final h (pre-f16-rounding): strictly closer to ref
  h_enc[(b0 + bat) * H + u] = h_last;
}

// ===================== decoder =====================
// Wide form (validated ~117us, R19): one lane per batch, 16 waves, grid 16,
// latency floor = two dependent trans rounds per step on the h->c->h chain.
// Gate constants pre-scaled by -L2E / +2L2E; c kept in 2L2E domain; h
// recurrence explicit. UNTOUCHED this round (matched prediction in R19).
__global__ __launch_bounds__(64) void decoder_kernel(
    const float* __restrict__ h_enc,  // [BATCH, 64]
    const float* __restrict__ Wih,    // [4, 64]
    const float* __restrict__ Whh,    // [4, 1]
    const float* __restrict__ bih,    // [4]
    const float* __restrict__ bhh,    // [4]
    float* __restrict__ out)          // [T, BATCH]
{
  const int b = blockIdx.x * blockDim.x + threadIdx.x;

  float a0 = bih[0] + bhh[0];
  float a1 = bih[1] + bhh[1];
  float a2 = bih[2] + bhh[2];
  float a3 = bih[3] + bhh[3];
#pragma unroll 8
  for (int k = 0; k < H; ++k) {
    const float hv = h_enc[b * H + k];
    a0 = fmaf(Wih[0 * H + k], hv, a0);
    a1 = fmaf(Wih[1 * H + k], hv, a1);
    a2 = fmaf(Wih[2 * H + k], hv, a2);
    a3 = fmaf(Wih[3 * H + k], hv, a3);
  }
  // exp2-domain constants: sigmoid gates scaled by -L2E, tanh gate +2*L2E
  const float wS0 = -L2E * Whh[0],     aS0 = -L2E * a0;      // i
  const float wS1 = -L2E * Whh[1],     aS1 = -L2E * a1;      // f
  const float wS2 = TWO_L2E * Whh[2],  aS2 = TWO_L2E * a2;   // g
  const float wS3 = -L2E * Whh[3],     aS3 = -L2E * a3;      // o

  float h = 0.0f, cs = 0.0f;   // cs = 2*log2e * c
  float* outp = out + b;
  for (int t = 0; t < T_LEN; t += 8) {
    float buf[8];
#pragma unroll
    for (int uu = 0; uu < 8; ++uu) {
      const float pi = exp2f_fast(fmaf(wS0, h, aS0));
      const float pf = exp2f_fast(fmaf(wS1, h, aS1));
      const float rg = exp2f_fast(fmaf(wS2, h, aS2));
      const float po = exp2f_fast(fmaf(wS3, h, aS3));
      const float iv = fast_rcp(1.0f + pi);
      const float fv = fast_rcp(1.0f + pf);
      const float ov = fast_rcp(1.0f + po);
      const float gm = fmaf(rg, TWO_L2E, -TWO_L2E);      // 2L2E*(rg-1)
      const float gt = gm * fast_rcp(rg + 1.0f);         // 2L2E*tanh(G2)
      cs = fmaf(fv, cs, iv * gt);
      const float s  = exp2f_fast(cs);                   // e^{2c}
      const float tc = fast_rcp(1.0f + s);
      h = fmaf(-2.0f * ov, tc, ov);                      // ov * tanh(c)
      buf[uu] = h;
    }
#pragma unroll
    for (int uu = 0; uu < 8; ++uu)
      outp[(t + uu) * BATCH] = buf[uu];
  }
}

extern "C" void kernel_launch(void* const* d_in, const int* in_sizes, int n_in,
                              void* d_out, int out_size, void* d_ws, size_t ws_size,
                              hipStream_t stream) {
  const float* x     = (const float*)d_in[0];
  const float* Wih_e = (const float*)d_in[1];
  const float* Whh_e = (const float*)d_in[2];
  const float* bih_e = (const float*)d_in[3];
  const float* bhh_e = (const float*)d_in[4];
  const float* Wih_d = (const float*)d_in[5];
  const float* Whh_d = (const float*)d_in[6];
  const float* bih_d = (const float*)d_in[7];
  const float* bhh_d = (const float*)d_in[8];
  float* out = (float*)d_out;

  float* h_enc = (float*)d_ws;  // 1024*64*4 = 256 KB scratch

  encoder_kernel<<<BATCH / NB, 256, 0, stream>>>(x, Wih_e, Whh_e, bih_e, bhh_e, h_enc);
  decoder_kernel<<<BATCH / 64, 64, 0, stream>>>(h_enc, Wih_d, Whh_d, bih_d, bhh_d, out);
}